// Round 7
// baseline (336.968 us; speedup 1.0000x reference)
//
#include <hip/hip_runtime.h>
#include <hip/hip_bf16.h>

#define NN 16384
#define NE 524288
#define FIN 256
#define HH1 64
#define HH2 32

typedef __attribute__((ext_vector_type(8))) short bf16x8;
typedef __attribute__((ext_vector_type(4))) float f32x4;

// ---------------- H0 = x @ W1  ([16384,256] @ [256,64]); extra blocks zero cnt ----------------
__global__ __launch_bounds__(256) void gemm_xw1_zero(const float* __restrict__ x,
                                                     const float* __restrict__ W1,
                                                     float* __restrict__ H0,
                                                     int* __restrict__ cnt) {
  if (blockIdx.x >= 256) {                       // 64 trailing blocks: zero cnt[16384]
    int i = (blockIdx.x - 256) * 256 + threadIdx.x;
    cnt[i] = 0;
    return;
  }
  __shared__ float xs[64][65];
  __shared__ float ws[64][65];
  const int t = threadIdx.x;
  const int row0 = blockIdx.x * 64;
  const int tr = t >> 4, tc = t & 15;
  float acc[4][4] = {};
  for (int kc = 0; kc < FIN; kc += 64) {
#pragma unroll
    for (int i = 0; i < 4; ++i) {
      int slot = t + i * 256;
      int r = slot >> 4, c4 = (slot & 15) * 4;
      float4 v = *reinterpret_cast<const float4*>(&x[(size_t)(row0 + r) * FIN + kc + c4]);
      xs[r][c4 + 0] = v.x; xs[r][c4 + 1] = v.y; xs[r][c4 + 2] = v.z; xs[r][c4 + 3] = v.w;
      float4 wv = *reinterpret_cast<const float4*>(&W1[(size_t)(kc + r) * HH1 + c4]);
      ws[r][c4 + 0] = wv.x; ws[r][c4 + 1] = wv.y; ws[r][c4 + 2] = wv.z; ws[r][c4 + 3] = wv.w;
    }
    __syncthreads();
#pragma unroll
    for (int k = 0; k < 64; ++k) {
      float a[4], b[4];
#pragma unroll
      for (int i = 0; i < 4; ++i) a[i] = xs[tr * 4 + i][k];
#pragma unroll
      for (int j = 0; j < 4; ++j) b[j] = ws[k][tc * 4 + j];
#pragma unroll
      for (int i = 0; i < 4; ++i)
#pragma unroll
        for (int j = 0; j < 4; ++j) acc[i][j] += a[i] * b[j];
    }
    __syncthreads();
  }
#pragma unroll
  for (int i = 0; i < 4; ++i) {
    float4 o; o.x = acc[i][0]; o.y = acc[i][1]; o.z = acc[i][2]; o.w = acc[i][3];
    *reinterpret_cast<float4*>(&H0[(size_t)(row0 + tr * 4 + i) * HH1 + tc * 4]) = o;
  }
}

// ---------------- counting sort of edges by src ----------------
__global__ __launch_bounds__(256) void hist_src(const int* __restrict__ src,
                                                int* __restrict__ cnt) {
  int e = blockIdx.x * 256 + threadIdx.x;
  if (e < NE) atomicAdd(&cnt[src[e]], 1);
}

// single block, 256 threads: vector loads + shuffle scan
__global__ __launch_bounds__(256) void scan_offsets(const int* __restrict__ cnt,
                                                    int* __restrict__ off,
                                                    int* __restrict__ cur) {
  __shared__ int wsum[4];
  __shared__ int wpre[4];
  const int t = threadIdx.x;
  const int lane = t & 63, w = t >> 6;
  int v[64];
#pragma unroll
  for (int i = 0; i < 16; ++i) {
    int4 q = reinterpret_cast<const int4*>(cnt)[t * 16 + i];
    v[i * 4 + 0] = q.x; v[i * 4 + 1] = q.y; v[i * 4 + 2] = q.z; v[i * 4 + 3] = q.w;
  }
  int s = 0;
#pragma unroll
  for (int i = 0; i < 64; ++i) s += v[i];
  int incl = s;
#pragma unroll
  for (int d = 1; d < 64; d <<= 1) {
    int n = __shfl_up(incl, d, 64);
    if (lane >= d) incl += n;
  }
  if (lane == 63) wsum[w] = incl;
  __syncthreads();
  if (t == 0) {
    int run = 0;
    for (int i = 0; i < 4; ++i) { int x = wsum[i]; wpre[i] = run; run += x; }
  }
  __syncthreads();
  int run = incl - s + wpre[w];
#pragma unroll
  for (int i = 0; i < 16; ++i) {
    int4 o;
    o.x = run; run += v[i * 4 + 0];
    o.y = run; run += v[i * 4 + 1];
    o.z = run; run += v[i * 4 + 2];
    o.w = run; run += v[i * 4 + 3];
    reinterpret_cast<int4*>(off)[t * 16 + i] = o;
    reinterpret_cast<int4*>(cur)[t * 16 + i] = o;
  }
  if (t == 255) off[NN] = run;   // == NE
}

__global__ __launch_bounds__(256) void scatter_edges(const int* __restrict__ src,
                                                     const int* __restrict__ dst,
                                                     const float* __restrict__ w,
                                                     int* __restrict__ cur,
                                                     int* __restrict__ sdst,
                                                     float* __restrict__ sw) {
  int e = blockIdx.x * 256 + threadIdx.x;
  if (e < NE) {
    int s = src[e];
    int p = atomicAdd(&cur[s], 1);
    sdst[p] = dst[e];
    sw[p] = w[e];
  }
}

// ---------------- fused: h = spmm(H0); G = h @ [W2|W3] ----------------
__global__ __launch_bounds__(256) void spmm_g(const int* __restrict__ off,
                                              const int* __restrict__ sdst,
                                              const float* __restrict__ sw,
                                              const float* __restrict__ Hin,
                                              const float* __restrict__ W2,
                                              const float* __restrict__ W3,
                                              float* __restrict__ G) {
  __shared__ float wsh[64][64];   // cols 0-31 = W2, 32-63 = W3
  __shared__ float hsh[4][64];
  const int t = threadIdx.x;
  for (int i = t; i < 64 * 32; i += 256) {
    int k = i >> 5, c = i & 31;
    wsh[k][c]      = W2[i];
    wsh[k][c + 32] = W3[i];
  }
  const int node = blockIdx.x * 4 + (t >> 6);
  const int lane = t & 63;
  const int beg = off[node], end = off[node + 1];
  float acc = 0.f;
  int e = beg;
  for (; e + 4 <= end; e += 4) {
    int d0 = sdst[e], d1 = sdst[e + 1], d2 = sdst[e + 2], d3 = sdst[e + 3];
    float w0 = sw[e], w1 = sw[e + 1], w2 = sw[e + 2], w3 = sw[e + 3];
    acc += w0 * Hin[(size_t)d0 * 64 + lane];
    acc += w1 * Hin[(size_t)d1 * 64 + lane];
    acc += w2 * Hin[(size_t)d2 * 64 + lane];
    acc += w3 * Hin[(size_t)d3 * 64 + lane];
  }
  for (; e < end; ++e) acc += sw[e] * Hin[(size_t)sdst[e] * 64 + lane];
  hsh[t >> 6][lane] = acc;
  __syncthreads();
  float g = 0.f;
#pragma unroll
  for (int k = 0; k < 64; ++k) g += hsh[t >> 6][k] * wsh[k][lane];
  G[(size_t)node * 64 + lane] = g;
}

// ---------------- fused: [zmean|zlog] = spmm(G); ztb = ((zmean*R)@M)*R ----------------
__global__ __launch_bounds__(256) void spmm_zt(const int* __restrict__ off,
                                               const int* __restrict__ sdst,
                                               const float* __restrict__ sw,
                                               const float* __restrict__ G,
                                               const float* __restrict__ R,
                                               const float* __restrict__ M,
                                               float* __restrict__ zmean,
                                               float* __restrict__ zlog,
                                               __hip_bfloat16* __restrict__ ztb) {
  __shared__ float Ms[32][33];
  __shared__ float zr[4][32];
  const int t = threadIdx.x;
  for (int i = t; i < 1024; i += 256) Ms[i >> 5][i & 31] = M[i];
  const int wv = t >> 6, lane = t & 63;
  const int node = blockIdx.x * 4 + wv;
  const int beg = off[node], end = off[node + 1];
  float acc = 0.f;
  int e = beg;
  for (; e + 4 <= end; e += 4) {
    int d0 = sdst[e], d1 = sdst[e + 1], d2 = sdst[e + 2], d3 = sdst[e + 3];
    float w0 = sw[e], w1 = sw[e + 1], w2 = sw[e + 2], w3 = sw[e + 3];
    acc += w0 * G[(size_t)d0 * 64 + lane];
    acc += w1 * G[(size_t)d1 * 64 + lane];
    acc += w2 * G[(size_t)d2 * 64 + lane];
    acc += w3 * G[(size_t)d3 * 64 + lane];
  }
  for (; e < end; ++e) acc += sw[e] * G[(size_t)sdst[e] * 64 + lane];
  if (lane < 32) {
    zmean[(size_t)node * 32 + lane] = acc;
    zr[wv][lane] = acc * R[lane];
  } else {
    zlog[(size_t)node * 32 + (lane - 32)] = acc;
  }
  __syncthreads();
  if (lane < 32) {
    float zt = 0.f;
#pragma unroll
    for (int k = 0; k < 32; ++k) zt += zr[wv][k] * Ms[k][lane];
    ztb[(size_t)node * 32 + lane] = __float2bfloat16(zt * R[lane]);
  }
}

// ---------------- adj = zt @ zt^T ----------------
// Stream-structured: block = 16-row band x all 16384 cols (grid 1024, all
// resident, 4 blocks/CU). Per 512-col super-tile: 4 waves compute 8 MFMAs
// each into a shared 16x512 LDS tile (16B units XOR-swizzled by row&7),
// barrier, then 256 threads write 8 rounds of 2 rows x 2KB contiguous.
// Each (block,row) is a sequential stream; ~2048 concurrent 2KB-chunk
// streams = the fill kernel's profile (~6.5 TB/s).
__global__ __launch_bounds__(256) void adj_mfma(const __hip_bfloat16* __restrict__ ztb,
                                                float* __restrict__ adj) {
  __shared__ float tile[16][512];              // 32 KB
  const int t = threadIdx.x;
  const int wave = t >> 6;
  const int lane = t & 63;
  const int l15 = lane & 15;
  const int kblk = lane >> 4;                  // 0..3
  const int rbase = blockIdx.x * 16;
  const short* zs = reinterpret_cast<const short*>(ztb);

  // B fragment (this band's 16 output rows): B[k][j] = zt[rbase+j][k]
  bf16x8 b0 = *reinterpret_cast<const bf16x8*>(&zs[(size_t)(rbase + l15) * 32 + kblk * 8]);

  const int prow = t >> 7;                     // phase-2: row parity within round
  const int pk = t & 127;                      // phase-2: 16B col unit

  for (int cstep = 0; cstep < 32; ++cstep) {
    const int c0 = cstep * 512;
    // Phase 1: wave covers cols [c0 + wave*128, +128) = 8 MFMA col-tiles.
    // lane holds adj[rbase+l15][c0 + wave*128 + tc*16 + kblk*4 + (0..3)]
#pragma unroll
    for (int tc = 0; tc < 8; ++tc) {
      const int acol = c0 + wave * 128 + tc * 16 + l15;
      bf16x8 a = *reinterpret_cast<const bf16x8*>(&zs[(size_t)acol * 32 + kblk * 8]);
      f32x4 z4 = {0.f, 0.f, 0.f, 0.f};
      f32x4 d = __builtin_amdgcn_mfma_f32_16x16x32_bf16(a, b0, z4, 0, 0, 0);
      const int u = wave * 32 + tc * 4 + kblk;       // logical 16B unit in [0,128)
      const int pu = u ^ (l15 & 7);                  // swizzle
      *reinterpret_cast<f32x4*>(&tile[l15][pu * 4]) = d;
    }
    __syncthreads();
    // Phase 2: 8 rounds; round r writes rows 2r,2r+1, 2 KB contiguous per row.
#pragma unroll
    for (int r = 0; r < 8; ++r) {
      const int row = r * 2 + prow;
      const int pu = pk ^ (row & 7);                 // inverse swizzle
      f32x4 v = *reinterpret_cast<const f32x4*>(&tile[row][pu * 4]);
      *reinterpret_cast<f32x4*>(&adj[(size_t)(rbase + row) * NN + c0 + pk * 4]) = v;
    }
    __syncthreads();
  }
}

// ---------------- launcher ----------------
extern "C" void kernel_launch(void* const* d_in, const int* in_sizes, int n_in,
                              void* d_out, int out_size, void* d_ws, size_t ws_size,
                              hipStream_t stream) {
  (void)in_sizes; (void)n_in; (void)out_size; (void)ws_size;

  const float* x   = (const float*)d_in[0];
  const float* ew  = (const float*)d_in[1];
  const float* W1  = (const float*)d_in[2];
  const float* W2  = (const float*)d_in[3];
  const float* W3  = (const float*)d_in[4];
  const float* R   = (const float*)d_in[5];
  const float* M   = (const float*)d_in[6];
  const int* esrc  = (const int*)d_in[7];
  const int* edst  = (const int*)d_in[8];

  float* adj_out   = (float*)d_out;
  float* zmean_out = adj_out + (size_t)NN * NN;
  float* zlog_out  = zmean_out + (size_t)NN * HH2;

  char* p = (char*)d_ws;
  float* H0 = (float*)p;                 p += (size_t)NN * HH1 * 4;   // 4 MB
  float* G  = (float*)p;                 p += (size_t)NN * HH1 * 4;   // 4 MB
  __hip_bfloat16* ztb = (__hip_bfloat16*)p; p += (size_t)NN * HH2 * 2; // 1 MB
  int* cnt  = (int*)p;                   p += (size_t)NN * 4;
  int* off  = (int*)p;                   p += (size_t)(NN + 4) * 4;
  int* cur  = (int*)p;                   p += (size_t)NN * 4;
  int* sdst = (int*)p;                   p += (size_t)NE * 4;         // 2 MB
  float* sw = (float*)p;                 p += (size_t)NE * 4;         // 2 MB

  gemm_xw1_zero<<<320, 256, 0, stream>>>(x, W1, H0, cnt);
  hist_src<<<NE / 256, 256, 0, stream>>>(esrc, cnt);
  scan_offsets<<<1, 256, 0, stream>>>(cnt, off, cur);
  scatter_edges<<<NE / 256, 256, 0, stream>>>(esrc, edst, ew, cur, sdst, sw);
  spmm_g<<<NN / 4, 256, 0, stream>>>(off, sdst, sw, H0, W2, W3, G);
  spmm_zt<<<NN / 4, 256, 0, stream>>>(off, sdst, sw, G, R, M,
                                      zmean_out, zlog_out, ztb);

  adj_mfma<<<NN / 16, 256, 0, stream>>>(ztb, adj_out);
}

// Round 8
// 319.565 us; speedup vs baseline: 1.0545x; 1.0545x over previous
//
#include <hip/hip_runtime.h>
#include <hip/hip_bf16.h>

#define NN 16384
#define NE 524288
#define FIN 256
#define HH1 64
#define HH2 32

typedef __attribute__((ext_vector_type(8))) short bf16x8;
typedef __attribute__((ext_vector_type(4))) float f32x4;

// ---------------- H0 = x @ W1; trailing blocks zero cnt ----------------
__global__ __launch_bounds__(256) void gemm_xw1_zero(const float* __restrict__ x,
                                                     const float* __restrict__ W1,
                                                     float* __restrict__ H0,
                                                     int* __restrict__ cnt) {
  if (blockIdx.x >= 256) {                       // 64 trailing blocks: zero cnt[16384]
    int i = (blockIdx.x - 256) * 256 + threadIdx.x;
    cnt[i] = 0;
    return;
  }
  __shared__ float xs[64][65];
  __shared__ float ws[64][65];
  const int t = threadIdx.x;
  const int row0 = blockIdx.x * 64;
  const int tr = t >> 4, tc = t & 15;
  float acc[4][4] = {};
  for (int kc = 0; kc < FIN; kc += 64) {
#pragma unroll
    for (int i = 0; i < 4; ++i) {
      int slot = t + i * 256;
      int r = slot >> 4, c4 = (slot & 15) * 4;
      float4 v = *reinterpret_cast<const float4*>(&x[(size_t)(row0 + r) * FIN + kc + c4]);
      xs[r][c4 + 0] = v.x; xs[r][c4 + 1] = v.y; xs[r][c4 + 2] = v.z; xs[r][c4 + 3] = v.w;
      float4 wv = *reinterpret_cast<const float4*>(&W1[(size_t)(kc + r) * HH1 + c4]);
      ws[r][c4 + 0] = wv.x; ws[r][c4 + 1] = wv.y; ws[r][c4 + 2] = wv.z; ws[r][c4 + 3] = wv.w;
    }
    __syncthreads();
#pragma unroll
    for (int k = 0; k < 64; ++k) {
      float a[4], b[4];
#pragma unroll
      for (int i = 0; i < 4; ++i) a[i] = xs[tr * 4 + i][k];
#pragma unroll
      for (int j = 0; j < 4; ++j) b[j] = ws[k][tc * 4 + j];
#pragma unroll
      for (int i = 0; i < 4; ++i)
#pragma unroll
        for (int j = 0; j < 4; ++j) acc[i][j] += a[i] * b[j];
    }
    __syncthreads();
  }
#pragma unroll
  for (int i = 0; i < 4; ++i) {
    float4 o; o.x = acc[i][0]; o.y = acc[i][1]; o.z = acc[i][2]; o.w = acc[i][3];
    *reinterpret_cast<float4*>(&H0[(size_t)(row0 + tr * 4 + i) * HH1 + tc * 4]) = o;
  }
}

// ---------------- counting sort of edges by src ----------------
__global__ __launch_bounds__(256) void hist_src(const int* __restrict__ src,
                                                int* __restrict__ cnt) {
  int e = blockIdx.x * 256 + threadIdx.x;
  if (e < NE) atomicAdd(&cnt[src[e]], 1);
}

// single block, 256 threads: vector loads + shuffle scan
__global__ __launch_bounds__(256) void scan_offsets(const int* __restrict__ cnt,
                                                    int* __restrict__ off,
                                                    int* __restrict__ cur) {
  __shared__ int wsum[4];
  __shared__ int wpre[4];
  const int t = threadIdx.x;
  const int lane = t & 63, w = t >> 6;
  int v[64];
#pragma unroll
  for (int i = 0; i < 16; ++i) {
    int4 q = reinterpret_cast<const int4*>(cnt)[t * 16 + i];
    v[i * 4 + 0] = q.x; v[i * 4 + 1] = q.y; v[i * 4 + 2] = q.z; v[i * 4 + 3] = q.w;
  }
  int s = 0;
#pragma unroll
  for (int i = 0; i < 64; ++i) s += v[i];
  int incl = s;
#pragma unroll
  for (int d = 1; d < 64; d <<= 1) {
    int n = __shfl_up(incl, d, 64);
    if (lane >= d) incl += n;
  }
  if (lane == 63) wsum[w] = incl;
  __syncthreads();
  if (t == 0) {
    int run = 0;
    for (int i = 0; i < 4; ++i) { int x = wsum[i]; wpre[i] = run; run += x; }
  }
  __syncthreads();
  int run = incl - s + wpre[w];
#pragma unroll
  for (int i = 0; i < 16; ++i) {
    int4 o;
    o.x = run; run += v[i * 4 + 0];
    o.y = run; run += v[i * 4 + 1];
    o.z = run; run += v[i * 4 + 2];
    o.w = run; run += v[i * 4 + 3];
    reinterpret_cast<int4*>(off)[t * 16 + i] = o;
    reinterpret_cast<int4*>(cur)[t * 16 + i] = o;
  }
  if (t == 255) off[NN] = run;   // == NE
}

__global__ __launch_bounds__(256) void scatter_edges(const int* __restrict__ src,
                                                     const int* __restrict__ dst,
                                                     const float* __restrict__ w,
                                                     int* __restrict__ cur,
                                                     int* __restrict__ sdst,
                                                     float* __restrict__ sw) {
  int e = blockIdx.x * 256 + threadIdx.x;
  if (e < NE) {
    int s = src[e];
    int p = atomicAdd(&cur[s], 1);
    sdst[p] = dst[e];
    sw[p] = w[e];
  }
}

// ---------------- fused: h = spmm(H0); G = h @ [W2|W3] ----------------
__global__ __launch_bounds__(256) void spmm_g(const int* __restrict__ off,
                                              const int* __restrict__ sdst,
                                              const float* __restrict__ sw,
                                              const float* __restrict__ Hin,
                                              const float* __restrict__ W2,
                                              const float* __restrict__ W3,
                                              float* __restrict__ G) {
  __shared__ float wsh[64][64];   // cols 0-31 = W2, 32-63 = W3
  __shared__ float hsh[4][64];
  const int t = threadIdx.x;
  for (int i = t; i < 64 * 32; i += 256) {
    int k = i >> 5, c = i & 31;
    wsh[k][c]      = W2[i];
    wsh[k][c + 32] = W3[i];
  }
  const int node = blockIdx.x * 4 + (t >> 6);
  const int lane = t & 63;
  const int beg = off[node], end = off[node + 1];
  float acc = 0.f;
  int e = beg;
  for (; e + 4 <= end; e += 4) {
    int d0 = sdst[e], d1 = sdst[e + 1], d2 = sdst[e + 2], d3 = sdst[e + 3];
    float w0 = sw[e], w1 = sw[e + 1], w2 = sw[e + 2], w3 = sw[e + 3];
    acc += w0 * Hin[(size_t)d0 * 64 + lane];
    acc += w1 * Hin[(size_t)d1 * 64 + lane];
    acc += w2 * Hin[(size_t)d2 * 64 + lane];
    acc += w3 * Hin[(size_t)d3 * 64 + lane];
  }
  for (; e < end; ++e) acc += sw[e] * Hin[(size_t)sdst[e] * 64 + lane];
  hsh[t >> 6][lane] = acc;
  __syncthreads();
  float g = 0.f;
#pragma unroll
  for (int k = 0; k < 64; ++k) g += hsh[t >> 6][k] * wsh[k][lane];
  G[(size_t)node * 64 + lane] = g;
}

// ---------------- fused: [zmean|zlog] = spmm(G); ztb = ((zmean*R)@M)*R ----------------
__global__ __launch_bounds__(256) void spmm_zt(const int* __restrict__ off,
                                               const int* __restrict__ sdst,
                                               const float* __restrict__ sw,
                                               const float* __restrict__ G,
                                               const float* __restrict__ R,
                                               const float* __restrict__ M,
                                               float* __restrict__ zmean,
                                               float* __restrict__ zlog,
                                               __hip_bfloat16* __restrict__ ztb) {
  __shared__ float Ms[32][33];
  __shared__ float zr[4][32];
  const int t = threadIdx.x;
  for (int i = t; i < 1024; i += 256) Ms[i >> 5][i & 31] = M[i];
  const int wv = t >> 6, lane = t & 63;
  const int node = blockIdx.x * 4 + wv;
  const int beg = off[node], end = off[node + 1];
  float acc = 0.f;
  int e = beg;
  for (; e + 4 <= end; e += 4) {
    int d0 = sdst[e], d1 = sdst[e + 1], d2 = sdst[e + 2], d3 = sdst[e + 3];
    float w0 = sw[e], w1 = sw[e + 1], w2 = sw[e + 2], w3 = sw[e + 3];
    acc += w0 * G[(size_t)d0 * 64 + lane];
    acc += w1 * G[(size_t)d1 * 64 + lane];
    acc += w2 * G[(size_t)d2 * 64 + lane];
    acc += w3 * G[(size_t)d3 * 64 + lane];
  }
  for (; e < end; ++e) acc += sw[e] * G[(size_t)sdst[e] * 64 + lane];
  if (lane < 32) {
    zmean[(size_t)node * 32 + lane] = acc;
    zr[wv][lane] = acc * R[lane];
  } else {
    zlog[(size_t)node * 32 + (lane - 32)] = acc;
  }
  __syncthreads();
  if (lane < 32) {
    float zt = 0.f;
#pragma unroll
    for (int k = 0; k < 32; ++k) zt += zr[wv][k] * Ms[k][lane];
    ztb[(size_t)node * 32 + lane] = __float2bfloat16(zt * R[lane]);
  }
}

// ---------------- adj = zt @ zt^T ----------------
// R5 structure (best so far, 324 us): 64r x 128c block tile, 4 waves,
// two 64-col halves, wave-private LDS, no barriers, full occupancy.
// SINGLE CHANGE vs R5: phase-2 stores are nontemporal (L2 no-allocate).
// Stores are 4 rows x 256 B contiguous = full 128 B sectors, so NT cannot
// create partial-line bursts (unlike R2's 64 B segments).
__global__ __launch_bounds__(256) void adj_mfma(const __hip_bfloat16* __restrict__ ztb,
                                                float* __restrict__ adj) {
  __shared__ float lds[4][16][64];             // 16 KB
  const int wave = threadIdx.x >> 6;
  const int lane = threadIdx.x & 63;
  const int l15 = lane & 15;
  const int kblk = lane >> 4;                  // 0..3
  const int rbase = blockIdx.y * 64 + wave * 16;
  const int cbase = blockIdx.x * 128;
  const short* zs = reinterpret_cast<const short*>(ztb);

  // B fragment (wave's 16 output rows): B[k][j] = zt[rbase+j][k]
  bf16x8 b0 = *reinterpret_cast<const bf16x8*>(&zs[(size_t)(rbase + l15) * 32 + kblk * 8]);

  const int j = lane & 15;                     // phase-2 col group (16 x 16B = 256B row)
  const int rl = lane >> 4;                    // phase-2 row within group of 4

#pragma unroll
  for (int half = 0; half < 2; ++half) {
    const int c0 = cbase + half * 64;
    // Phase 1: lane computes adj[rbase+l15][c0 + tc*16 + kblk*4 + (0..3)]
#pragma unroll
    for (int tc = 0; tc < 4; ++tc) {
      bf16x8 a = *reinterpret_cast<const bf16x8*>(
          &zs[(size_t)(c0 + tc * 16 + l15) * 32 + kblk * 8]);
      f32x4 z4 = {0.f, 0.f, 0.f, 0.f};
      f32x4 d = __builtin_amdgcn_mfma_f32_16x16x32_bf16(a, b0, z4, 0, 0, 0);
      int unit = (tc * 4 + kblk) ^ l15;        // 16 units/row, XOR involution
      *reinterpret_cast<f32x4*>(&lds[wave][l15][unit * 4]) = d;
    }
    // Phase 2: 4 iterations x (4 rows x 256 B) = 16 rows x 64 cols
#pragma unroll
    for (int it = 0; it < 4; ++it) {
      const int row = it * 4 + rl;
      int unit = j ^ row;                      // inverse swizzle
      f32x4 v = *reinterpret_cast<const f32x4*>(&lds[wave][row][unit * 4]);
      __builtin_nontemporal_store(
          v, reinterpret_cast<f32x4*>(&adj[(size_t)(rbase + row) * NN + c0 + j * 4]));
    }
  }
}

// ---------------- launcher ----------------
extern "C" void kernel_launch(void* const* d_in, const int* in_sizes, int n_in,
                              void* d_out, int out_size, void* d_ws, size_t ws_size,
                              hipStream_t stream) {
  (void)in_sizes; (void)n_in; (void)out_size; (void)ws_size;

  const float* x   = (const float*)d_in[0];
  const float* ew  = (const float*)d_in[1];
  const float* W1  = (const float*)d_in[2];
  const float* W2  = (const float*)d_in[3];
  const float* W3  = (const float*)d_in[4];
  const float* R   = (const float*)d_in[5];
  const float* M   = (const float*)d_in[6];
  const int* esrc  = (const int*)d_in[7];
  const int* edst  = (const int*)d_in[8];

  float* adj_out   = (float*)d_out;
  float* zmean_out = adj_out + (size_t)NN * NN;
  float* zlog_out  = zmean_out + (size_t)NN * HH2;

  char* p = (char*)d_ws;
  float* H0 = (float*)p;                 p += (size_t)NN * HH1 * 4;   // 4 MB
  float* G  = (float*)p;                 p += (size_t)NN * HH1 * 4;   // 4 MB
  __hip_bfloat16* ztb = (__hip_bfloat16*)p; p += (size_t)NN * HH2 * 2; // 1 MB
  int* cnt  = (int*)p;                   p += (size_t)NN * 4;
  int* off  = (int*)p;                   p += (size_t)(NN + 4) * 4;
  int* cur  = (int*)p;                   p += (size_t)NN * 4;
  int* sdst = (int*)p;                   p += (size_t)NE * 4;         // 2 MB
  float* sw = (float*)p;                 p += (size_t)NE * 4;         // 2 MB

  gemm_xw1_zero<<<320, 256, 0, stream>>>(x, W1, H0, cnt);
  hist_src<<<NE / 256, 256, 0, stream>>>(esrc, cnt);
  scan_offsets<<<1, 256, 0, stream>>>(cnt, off, cur);
  scatter_edges<<<NE / 256, 256, 0, stream>>>(esrc, edst, ew, cur, sdst, sw);
  spmm_g<<<NN / 4, 256, 0, stream>>>(off, sdst, sw, H0, W2, W3, G);
  spmm_zt<<<NN / 4, 256, 0, stream>>>(off, sdst, sw, G, R, M,
                                      zmean_out, zlog_out, ztb);

  dim3 g(NN / 128, NN / 64, 1);
  adj_mfma<<<g, 256, 0, stream>>>(ztb, adj_out);
}

// Round 9
// 297.620 us; speedup vs baseline: 1.1322x; 1.0737x over previous
//
#include <hip/hip_runtime.h>
#include <hip/hip_bf16.h>

#define NN 16384
#define NE 524288
#define FIN 256
#define HH1 64
#define HH2 32

typedef __attribute__((ext_vector_type(8))) short bf16x8;
typedef __attribute__((ext_vector_type(4))) float f32x4;

// ---------------- H0 = x @ W1; trailing blocks zero cnt ----------------
__global__ __launch_bounds__(256) void gemm_xw1_zero(const float* __restrict__ x,
                                                     const float* __restrict__ W1,
                                                     float* __restrict__ H0,
                                                     int* __restrict__ cnt) {
  if (blockIdx.x >= 256) {                       // 64 trailing blocks: zero cnt[16384]
    int i = (blockIdx.x - 256) * 256 + threadIdx.x;
    cnt[i] = 0;
    return;
  }
  __shared__ float xs[64][65];
  __shared__ float ws[64][65];
  const int t = threadIdx.x;
  const int row0 = blockIdx.x * 64;
  const int tr = t >> 4, tc = t & 15;
  float acc[4][4] = {};
  for (int kc = 0; kc < FIN; kc += 64) {
#pragma unroll
    for (int i = 0; i < 4; ++i) {
      int slot = t + i * 256;
      int r = slot >> 4, c4 = (slot & 15) * 4;
      float4 v = *reinterpret_cast<const float4*>(&x[(size_t)(row0 + r) * FIN + kc + c4]);
      xs[r][c4 + 0] = v.x; xs[r][c4 + 1] = v.y; xs[r][c4 + 2] = v.z; xs[r][c4 + 3] = v.w;
      float4 wv = *reinterpret_cast<const float4*>(&W1[(size_t)(kc + r) * HH1 + c4]);
      ws[r][c4 + 0] = wv.x; ws[r][c4 + 1] = wv.y; ws[r][c4 + 2] = wv.z; ws[r][c4 + 3] = wv.w;
    }
    __syncthreads();
#pragma unroll
    for (int k = 0; k < 64; ++k) {
      float a[4], b[4];
#pragma unroll
      for (int i = 0; i < 4; ++i) a[i] = xs[tr * 4 + i][k];
#pragma unroll
      for (int j = 0; j < 4; ++j) b[j] = ws[k][tc * 4 + j];
#pragma unroll
      for (int i = 0; i < 4; ++i)
#pragma unroll
        for (int j = 0; j < 4; ++j) acc[i][j] += a[i] * b[j];
    }
    __syncthreads();
  }
#pragma unroll
  for (int i = 0; i < 4; ++i) {
    float4 o; o.x = acc[i][0]; o.y = acc[i][1]; o.z = acc[i][2]; o.w = acc[i][3];
    *reinterpret_cast<float4*>(&H0[(size_t)(row0 + tr * 4 + i) * HH1 + tc * 4]) = o;
  }
}

// ---------------- counting sort of edges by src ----------------
__global__ __launch_bounds__(256) void hist_src(const int* __restrict__ src,
                                                int* __restrict__ cnt) {
  int e = blockIdx.x * 256 + threadIdx.x;
  if (e < NE) atomicAdd(&cnt[src[e]], 1);
}

// single block, 256 threads: vector loads + shuffle scan
__global__ __launch_bounds__(256) void scan_offsets(const int* __restrict__ cnt,
                                                    int* __restrict__ off,
                                                    int* __restrict__ cur) {
  __shared__ int wsum[4];
  __shared__ int wpre[4];
  const int t = threadIdx.x;
  const int lane = t & 63, w = t >> 6;
  int v[64];
#pragma unroll
  for (int i = 0; i < 16; ++i) {
    int4 q = reinterpret_cast<const int4*>(cnt)[t * 16 + i];
    v[i * 4 + 0] = q.x; v[i * 4 + 1] = q.y; v[i * 4 + 2] = q.z; v[i * 4 + 3] = q.w;
  }
  int s = 0;
#pragma unroll
  for (int i = 0; i < 64; ++i) s += v[i];
  int incl = s;
#pragma unroll
  for (int d = 1; d < 64; d <<= 1) {
    int n = __shfl_up(incl, d, 64);
    if (lane >= d) incl += n;
  }
  if (lane == 63) wsum[w] = incl;
  __syncthreads();
  if (t == 0) {
    int run = 0;
    for (int i = 0; i < 4; ++i) { int x = wsum[i]; wpre[i] = run; run += x; }
  }
  __syncthreads();
  int run = incl - s + wpre[w];
#pragma unroll
  for (int i = 0; i < 16; ++i) {
    int4 o;
    o.x = run; run += v[i * 4 + 0];
    o.y = run; run += v[i * 4 + 1];
    o.z = run; run += v[i * 4 + 2];
    o.w = run; run += v[i * 4 + 3];
    reinterpret_cast<int4*>(off)[t * 16 + i] = o;
    reinterpret_cast<int4*>(cur)[t * 16 + i] = o;
  }
  if (t == 255) off[NN] = run;   // == NE
}

__global__ __launch_bounds__(256) void scatter_edges(const int* __restrict__ src,
                                                     const int* __restrict__ dst,
                                                     const float* __restrict__ w,
                                                     int* __restrict__ cur,
                                                     int* __restrict__ sdst,
                                                     float* __restrict__ sw) {
  int e = blockIdx.x * 256 + threadIdx.x;
  if (e < NE) {
    int s = src[e];
    int p = atomicAdd(&cur[s], 1);
    sdst[p] = dst[e];
    sw[p] = w[e];
  }
}

// ---------------- fused: h = spmm(H0); G = h @ [W2|W3] ----------------
__global__ __launch_bounds__(256) void spmm_g(const int* __restrict__ off,
                                              const int* __restrict__ sdst,
                                              const float* __restrict__ sw,
                                              const float* __restrict__ Hin,
                                              const float* __restrict__ W2,
                                              const float* __restrict__ W3,
                                              float* __restrict__ G) {
  __shared__ float wsh[64][64];   // cols 0-31 = W2, 32-63 = W3
  __shared__ float hsh[4][64];
  const int t = threadIdx.x;
  for (int i = t; i < 64 * 32; i += 256) {
    int k = i >> 5, c = i & 31;
    wsh[k][c]      = W2[i];
    wsh[k][c + 32] = W3[i];
  }
  const int node = blockIdx.x * 4 + (t >> 6);
  const int lane = t & 63;
  const int beg = off[node], end = off[node + 1];
  float acc = 0.f;
  int e = beg;
  for (; e + 4 <= end; e += 4) {
    int d0 = sdst[e], d1 = sdst[e + 1], d2 = sdst[e + 2], d3 = sdst[e + 3];
    float w0 = sw[e], w1 = sw[e + 1], w2 = sw[e + 2], w3 = sw[e + 3];
    acc += w0 * Hin[(size_t)d0 * 64 + lane];
    acc += w1 * Hin[(size_t)d1 * 64 + lane];
    acc += w2 * Hin[(size_t)d2 * 64 + lane];
    acc += w3 * Hin[(size_t)d3 * 64 + lane];
  }
  for (; e < end; ++e) acc += sw[e] * Hin[(size_t)sdst[e] * 64 + lane];
  hsh[t >> 6][lane] = acc;
  __syncthreads();
  float g = 0.f;
#pragma unroll
  for (int k = 0; k < 64; ++k) g += hsh[t >> 6][k] * wsh[k][lane];
  G[(size_t)node * 64 + lane] = g;
}

// ---------------- fused: [zmean|zlog] = spmm(G); ztb = ((zmean*R)@M)*R ----------------
__global__ __launch_bounds__(256) void spmm_zt(const int* __restrict__ off,
                                               const int* __restrict__ sdst,
                                               const float* __restrict__ sw,
                                               const float* __restrict__ G,
                                               const float* __restrict__ R,
                                               const float* __restrict__ M,
                                               float* __restrict__ zmean,
                                               float* __restrict__ zlog,
                                               __hip_bfloat16* __restrict__ ztb) {
  __shared__ float Ms[32][33];
  __shared__ float zr[4][32];
  const int t = threadIdx.x;
  for (int i = t; i < 1024; i += 256) Ms[i >> 5][i & 31] = M[i];
  const int wv = t >> 6, lane = t & 63;
  const int node = blockIdx.x * 4 + wv;
  const int beg = off[node], end = off[node + 1];
  float acc = 0.f;
  int e = beg;
  for (; e + 4 <= end; e += 4) {
    int d0 = sdst[e], d1 = sdst[e + 1], d2 = sdst[e + 2], d3 = sdst[e + 3];
    float w0 = sw[e], w1 = sw[e + 1], w2 = sw[e + 2], w3 = sw[e + 3];
    acc += w0 * G[(size_t)d0 * 64 + lane];
    acc += w1 * G[(size_t)d1 * 64 + lane];
    acc += w2 * G[(size_t)d2 * 64 + lane];
    acc += w3 * G[(size_t)d3 * 64 + lane];
  }
  for (; e < end; ++e) acc += sw[e] * G[(size_t)sdst[e] * 64 + lane];
  if (lane < 32) {
    zmean[(size_t)node * 32 + lane] = acc;
    zr[wv][lane] = acc * R[lane];
  } else {
    zlog[(size_t)node * 32 + (lane - 32)] = acc;
  }
  __syncthreads();
  if (lane < 32) {
    float zt = 0.f;
#pragma unroll
    for (int k = 0; k < 32; ++k) zt += zr[wv][k] * Ms[k][lane];
    ztb[(size_t)node * 32 + lane] = __float2bfloat16(zt * R[lane]);
  }
}

// ---------------- adj = zt @ zt^T ----------------
// Fill-mimicking store geometry. Block = 16 rows x 1024 cols (grid 16x1024,
// short-lived blocks, dense frontier). Phase 1: 4 waves x 16 MFMAs fill a
// [16][1024] 64 KB LDS tile (16B units XOR-swizzled by row&7). Barrier.
// Phase 2: wave w owns rows [4w,4w+4); per row, 4 SEQUENTIAL nontemporal
// stores, each exactly 1 KB contiguous aligned (64 lanes x 16 B, single
// segment) — per-instruction footprint identical to the harness fill.
__global__ __launch_bounds__(256) void adj_mfma(const __hip_bfloat16* __restrict__ ztb,
                                                float* __restrict__ adj) {
  __shared__ float tile[16][1024];             // 64 KB
  const int t = threadIdx.x;
  const int wave = t >> 6;
  const int lane = t & 63;
  const int l15 = lane & 15;
  const int kblk = lane >> 4;                  // 0..3
  const int rbase = blockIdx.y * 16;
  const int cbase = blockIdx.x * 1024;
  const short* zs = reinterpret_cast<const short*>(ztb);

  // B fragment (the band's 16 output rows): B[k][j] = zt[rbase+j][k]
  bf16x8 b0 = *reinterpret_cast<const bf16x8*>(&zs[(size_t)(rbase + l15) * 32 + kblk * 8]);

  // Phase 1: wave w covers cols [cbase + w*256, +256) = 16 MFMA col-tiles.
  // lane(l15,kblk) reg e holds adj[rbase+l15][cbase + w*256 + tc*16 + kblk*4 + e]
#pragma unroll
  for (int tc = 0; tc < 16; ++tc) {
    const int acol = cbase + wave * 256 + tc * 16 + l15;
    bf16x8 a = *reinterpret_cast<const bf16x8*>(&zs[(size_t)acol * 32 + kblk * 8]);
    f32x4 z4 = {0.f, 0.f, 0.f, 0.f};
    f32x4 d = __builtin_amdgcn_mfma_f32_16x16x32_bf16(a, b0, z4, 0, 0, 0);
    const int u = wave * 64 + tc * 4 + kblk;   // logical 16B unit in [0,256)
    const int pu = u ^ (l15 & 7);              // swizzle
    *reinterpret_cast<f32x4*>(&tile[l15][pu * 4]) = d;
  }
  __syncthreads();

  // Phase 2: wave w writes rows 4w..4w+3; each row = 4 sequential 1KB stores.
#pragma unroll
  for (int rr = 0; rr < 4; ++rr) {
    const int row = wave * 4 + rr;
    float* dst = &adj[(size_t)(rbase + row) * NN + cbase];
#pragma unroll
    for (int seg = 0; seg < 4; ++seg) {
      const int u = seg * 64 + lane;           // logical 16B unit
      const int pu = u ^ (row & 7);            // inverse swizzle
      f32x4 v = *reinterpret_cast<const f32x4*>(&tile[row][pu * 4]);
      __builtin_nontemporal_store(
          v, reinterpret_cast<f32x4*>(dst + seg * 256 + lane * 4));
    }
  }
}

// ---------------- launcher ----------------
extern "C" void kernel_launch(void* const* d_in, const int* in_sizes, int n_in,
                              void* d_out, int out_size, void* d_ws, size_t ws_size,
                              hipStream_t stream) {
  (void)in_sizes; (void)n_in; (void)out_size; (void)ws_size;

  const float* x   = (const float*)d_in[0];
  const float* ew  = (const float*)d_in[1];
  const float* W1  = (const float*)d_in[2];
  const float* W2  = (const float*)d_in[3];
  const float* W3  = (const float*)d_in[4];
  const float* R   = (const float*)d_in[5];
  const float* M   = (const float*)d_in[6];
  const int* esrc  = (const int*)d_in[7];
  const int* edst  = (const int*)d_in[8];

  float* adj_out   = (float*)d_out;
  float* zmean_out = adj_out + (size_t)NN * NN;
  float* zlog_out  = zmean_out + (size_t)NN * HH2;

  char* p = (char*)d_ws;
  float* H0 = (float*)p;                 p += (size_t)NN * HH1 * 4;   // 4 MB
  float* G  = (float*)p;                 p += (size_t)NN * HH1 * 4;   // 4 MB
  __hip_bfloat16* ztb = (__hip_bfloat16*)p; p += (size_t)NN * HH2 * 2; // 1 MB
  int* cnt  = (int*)p;                   p += (size_t)NN * 4;
  int* off  = (int*)p;                   p += (size_t)(NN + 4) * 4;
  int* cur  = (int*)p;                   p += (size_t)NN * 4;
  int* sdst = (int*)p;                   p += (size_t)NE * 4;         // 2 MB
  float* sw = (float*)p;                 p += (size_t)NE * 4;         // 2 MB

  gemm_xw1_zero<<<320, 256, 0, stream>>>(x, W1, H0, cnt);
  hist_src<<<NE / 256, 256, 0, stream>>>(esrc, cnt);
  scan_offsets<<<1, 256, 0, stream>>>(cnt, off, cur);
  scatter_edges<<<NE / 256, 256, 0, stream>>>(esrc, edst, ew, cur, sdst, sw);
  spmm_g<<<NN / 4, 256, 0, stream>>>(off, sdst, sw, H0, W2, W3, G);
  spmm_zt<<<NN / 4, 256, 0, stream>>>(off, sdst, sw, G, R, M,
                                      zmean_out, zlog_out, ztb);

  dim3 g(NN / 1024, NN / 16, 1);
  adj_mfma<<<g, 256, 0, stream>>>(ztb, adj_out);
}